// Round 8
// baseline (33.686 us; speedup 1.0000x reference)
//
#include <hip/hip_runtime.h>

#define BB 8
#define NN 2048
#define FF 64
#define LOG2E 1.4426950408889634f
#define ROWS_PER_BLOCK 16

typedef float f32x4 __attribute__((ext_vector_type(4)));

__device__ __forceinline__ float waveMax(float v) {
    #pragma unroll
    for (int o = 32; o > 0; o >>= 1) v = fmaxf(v, __shfl_xor(v, o, 64));
    return v;
}
__device__ __forceinline__ float lk(float x) { return fmaxf(x, 0.2f * x); }
__device__ __forceinline__ f32x4 vmax4(f32x4 a, f32x4 b) {
    f32x4 r;
    r.x = fmaxf(a.x, b.x); r.y = fmaxf(a.y, b.y);
    r.z = fmaxf(a.z, b.z); r.w = fmaxf(a.w, b.w);
    return r;
}

// ---------------- Kernel A: fused fold + per-node scores (prescaled) ---------
__global__ __launch_bounds__(256) void scores_fused(const float* __restrict__ enc,
                                                    const float* __restrict__ kmat,
                                                    const float* __restrict__ aks,
                                                    const float* __restrict__ akn,
                                                    float* __restrict__ S,
                                                    float* __restrict__ T) {
    __shared__ float ws[FF], wn[FF];
    const int tid = threadIdx.x;
    if (tid < FF) {
        float s = 0.f, t = 0.f;
        #pragma unroll
        for (int o = 0; o < FF; ++o) {
            float k = kmat[tid * FF + o];
            s += k * aks[o];
            t += k * akn[o];
        }
        ws[tid] = s;
        wn[tid] = t;
    }
    __syncthreads();

    const int g = blockIdx.x * 256 + tid;
    const f32x4* e4 = (const f32x4*)(enc + (size_t)g * FF);
    const f32x4* w4 = (const f32x4*)ws;
    const f32x4* v4 = (const f32x4*)wn;
    float s = 0.f, t = 0.f;
    #pragma unroll
    for (int j = 0; j < FF / 4; ++j) {
        f32x4 e = e4[j];
        f32x4 w = w4[j];
        f32x4 v = v4[j];
        s += e.x * w.x + e.y * w.y + e.z * w.z + e.w * w.w;
        t += e.x * v.x + e.y * v.y + e.z * v.z + e.w * v.w;
    }
    S[g] = s * LOG2E;
    T[g] = t * LOG2E;
}

// ---------------- Kernel B: LDS-shared E/F, two-pass, all-resident grid ------
__global__ __launch_bounds__(256) void softmax_kernel(const float* __restrict__ S,
                                                      const float* __restrict__ T,
                                                      float* __restrict__ out) {
    __shared__ float Ez[NN];
    __shared__ float Fz[NN];
    __shared__ float wred[4];

    const int tid  = threadIdx.x;
    const int wave = tid >> 6, lane = tid & 63;
    const int row0 = blockIdx.x * ROWS_PER_BLOCK;  // 16 rows, one batch
    const int b    = row0 >> 11;                   // N = 2048

    // ---- Phase 1: block tmax + shared E/F tables (16 exp2 per thread) ----
    const f32x4* t4 = (const f32x4*)(T + (size_t)b * NN);
    f32x4 ta = t4[tid];         // elems 4*tid..4*tid+3
    f32x4 tb = t4[tid + 256];   // elems 1024+4*tid..
    float tm = fmaxf(fmaxf(fmaxf(ta.x, ta.y), fmaxf(ta.z, ta.w)),
                     fmaxf(fmaxf(tb.x, tb.y), fmaxf(tb.z, tb.w)));
    tm = waveMax(tm);
    if (lane == 0) wred[wave] = tm;
    __syncthreads();
    const float tmax = fmaxf(fmaxf(wred[0], wred[1]), fmaxf(wred[2], wred[3]));

    f32x4* EL = (f32x4*)Ez;
    f32x4* FL = (f32x4*)Fz;
    {
        f32x4 d, E, F;
        d.x = ta.x - tmax; d.y = ta.y - tmax; d.z = ta.z - tmax; d.w = ta.w - tmax;
        E.x = __builtin_exp2f(d.x); E.y = __builtin_exp2f(d.y);
        E.z = __builtin_exp2f(d.z); E.w = __builtin_exp2f(d.w);
        F.x = __builtin_exp2f(0.2f * d.x); F.y = __builtin_exp2f(0.2f * d.y);
        F.z = __builtin_exp2f(0.2f * d.z); F.w = __builtin_exp2f(0.2f * d.w);
        EL[tid] = E; FL[tid] = F;
        d.x = tb.x - tmax; d.y = tb.y - tmax; d.z = tb.z - tmax; d.w = tb.w - tmax;
        E.x = __builtin_exp2f(d.x); E.y = __builtin_exp2f(d.y);
        E.z = __builtin_exp2f(d.z); E.w = __builtin_exp2f(d.w);
        F.x = __builtin_exp2f(0.2f * d.x); F.y = __builtin_exp2f(0.2f * d.y);
        F.z = __builtin_exp2f(0.2f * d.z); F.w = __builtin_exp2f(0.2f * d.w);
        EL[tid + 256] = E; FL[tid + 256] = F;
    }
    __syncthreads();

    // ---- Phase 2a: denominators for this wave's 4 rows (sum pass) ----
    const int wrow0 = row0 + wave * 4;
    float A[4], Bc[4], ls[4];
    #pragma unroll
    for (int r = 0; r < 4; ++r) {
        const float s = S[wrow0 + r];
        const float u = s + tmax;
        const float M = lk(u);                        // exact rowmax
        A[r]  = __builtin_exp2f(u - M);               // pos-branch factor
        Bc[r] = __builtin_exp2f(0.2f * u - M);        // neg-branch factor
        float l = 0.f;
        #pragma unroll
        for (int j = 0; j < 8; ++j) {
            f32x4 E = EL[lane + 64 * j];
            f32x4 F = FL[lane + 64 * j];
            f32x4 e = vmax4(A[r] * E, Bc[r] * F);
            l += (e.x + e.y) + (e.z + e.w);
        }
        ls[r] = l;
    }
    // interleaved wave reductions: 4 independent chains overlap
    #pragma unroll
    for (int o = 32; o > 0; o >>= 1) {
        ls[0] += __shfl_xor(ls[0], o, 64);
        ls[1] += __shfl_xor(ls[1], o, 64);
        ls[2] += __shfl_xor(ls[2], o, 64);
        ls[3] += __shfl_xor(ls[3], o, 64);
    }
    #pragma unroll
    for (int r = 0; r < 4; ++r) {
        const float inv = __builtin_amdgcn_rcpf(ls[r]);
        A[r]  *= inv;   // fold normalization into the factors
        Bc[r] *= inv;
    }

    // ---- Phase 2b: pure store pass — 32 back-to-back 1 KB stores/wave ----
    #pragma unroll
    for (int r = 0; r < 4; ++r) {
        f32x4* o4 = (f32x4*)(out + (size_t)(wrow0 + r) * NN);
        #pragma unroll
        for (int j = 0; j < 8; ++j) {
            f32x4 E = EL[lane + 64 * j];
            f32x4 F = FL[lane + 64 * j];
            o4[lane + 64 * j] = vmax4(A[r] * E, Bc[r] * F);
        }
    }
}

extern "C" void kernel_launch(void* const* d_in, const int* in_sizes, int n_in,
                              void* d_out, int out_size, void* d_ws, size_t ws_size,
                              hipStream_t stream) {
    const float* enc  = (const float*)d_in[0];  // [B,N,F]
    const float* kmat = (const float*)d_in[1];  // [F,1,F]
    const float* aks  = (const float*)d_in[2];  // [F,1,1]
    const float* akn  = (const float*)d_in[3];  // [F,1,1]
    float* out = (float*)d_out;                 // [B,N,N]

    float* W = (float*)d_ws;
    float* S = W;                 // B*N = 16384
    float* T = W + BB * NN;       // 16384

    scores_fused<<<BB * NN / 256, 256, 0, stream>>>(enc, kmat, aks, akn, S, T);
    softmax_kernel<<<BB * NN / ROWS_PER_BLOCK, 256, 0, stream>>>(S, T, out);
}